// Round 9
// baseline (1163.357 us; speedup 1.0000x reference)
//
#include <hip/hip_runtime.h>

#define FPS_N 32768
#define FPS_M 2048
#define FPS_B 16
#define BLK_PER_B 8
#define FPS_T 576                 // 9 waves: wave 0 = comm, waves 1-8 = scan
#define SCT 512                   // scan threads
#define PTS (FPS_N / BLK_PER_B)   // 4096 points per block
#define PPT (PTS / SCT)           // 8 points per scan thread
#define KPUB 4                    // candidates published per wave
#define RING 128
#define WSTRIDE 1280              // 2x320 agent parity + 2x320 MIRROR parity

typedef unsigned long long ull;

// u64 max step via DPP (identity-safe: old = self). Verified rounds 11/15-17.
#define DPP_MAX_STEP(ctrl, rmask)                                              \
    {                                                                          \
        unsigned plo = (unsigned)__builtin_amdgcn_update_dpp(                  \
            (int)lo, (int)lo, (ctrl), (rmask), 0xf, false);                    \
        unsigned phi = (unsigned)__builtin_amdgcn_update_dpp(                  \
            (int)hi, (int)hi, (ctrl), (rmask), 0xf, false);                    \
        if (phi > hi || (phi == hi && plo > lo)) { hi = phi; lo = plo; }       \
    }

__device__ __forceinline__ ull wave_max_u64(ull v) {
    unsigned lo = (unsigned)v, hi = (unsigned)(v >> 32);
    DPP_MAX_STEP(0x111, 0xf)
    DPP_MAX_STEP(0x112, 0xf)
    DPP_MAX_STEP(0x114, 0xf)
    DPP_MAX_STEP(0x118, 0xf)
    DPP_MAX_STEP(0x142, 0xa)
    DPP_MAX_STEP(0x143, 0xc)
    unsigned blo = (unsigned)__builtin_amdgcn_readlane((int)lo, 63);
    unsigned bhi = (unsigned)__builtin_amdgcn_readlane((int)hi, 63);
    return ((ull)bhi << 32) | blo;
}

// Wave max of f32 BITS over the domain {non-negative f32, -1.0f sentinel}:
// signed-int order == float order there. 4 row_shr DPP steps accumulate the
// row max toward HIGHER lanes, so after 1/2/4/8 the row max sits in lane
// 15/31/47/63. Verified on HW (v8/v9/v11 runs, absmax 0.0).
__device__ __forceinline__ unsigned wave_max_bits(unsigned v) {
    int m = (int)v;
#define DPP_IMAX_STEP(ctrl)                                                    \
    {                                                                          \
        int p = __builtin_amdgcn_update_dpp((int)m, (int)m, (ctrl), 0xf, 0xf,  \
                                            false);                            \
        m = p > m ? p : m;                                                     \
    }
    DPP_IMAX_STEP(0x111)   // row_shr:1
    DPP_IMAX_STEP(0x112)   // row_shr:2
    DPP_IMAX_STEP(0x114)   // row_shr:4
    DPP_IMAX_STEP(0x118)   // row_shr:8 -> lane 15 of each row = row max
    int r0 = __builtin_amdgcn_readlane(m, 15);
    int r1 = __builtin_amdgcn_readlane(m, 31);
    int r2 = __builtin_amdgcn_readlane(m, 47);
    int r3 = __builtin_amdgcn_readlane(m, 63);
    int a = r0 > r1 ? r0 : r1;
    int bq = r2 > r3 ? r2 : r3;
    return (unsigned)(a > bq ? a : bq);
}

// u32 wave min (identity-safe), broadcast from lane 63. Rare-tie path only.
__device__ __forceinline__ unsigned wave_min_u32(unsigned v) {
    unsigned m = v;
#define DPP_UMIN_STEP(ctrl, rmask)                                             \
    {                                                                          \
        unsigned p = (unsigned)__builtin_amdgcn_update_dpp(                    \
            (int)m, (int)m, (ctrl), (rmask), 0xf, false);                      \
        if (p < m) m = p;                                                      \
    }
    DPP_UMIN_STEP(0x111, 0xf)
    DPP_UMIN_STEP(0x112, 0xf)
    DPP_UMIN_STEP(0x114, 0xf)
    DPP_UMIN_STEP(0x118, 0xf)
    DPP_UMIN_STEP(0x142, 0xa)
    DPP_UMIN_STEP(0x143, 0xc)
    return (unsigned)__builtin_amdgcn_readlane((int)m, 63);
}

__device__ __forceinline__ float readlane_f(float v, int l) {
    return __uint_as_float(
        (unsigned)__builtin_amdgcn_readlane((int)__float_as_uint(v), l));
}

// EXACT LAZY-BATCHED FPS v15 = v11 + PARITY-BUFFERED MIRROR + adaptive
// cadence. Post-mortems: v9 coalesced poll 1493->1157 / v11 dual-path
// 1157->1124 / v12 agent-throttle REGRESSED / v13 contiguous map REGRESSED
// (FETCH x12 => round-robin confirmed: batch b's 8 blocks all on XCD b%8) /
// v14 overlapped poll stages FLAT => poll period isn't the binding term.
// Reconciliation: under round-robin the whole batch shares one XCD, so the
// mirror should serve ALL words at L2 latency — yet v12 proved laggard
// comms needed the agent copy. Cause: the mirror was SINGLE-buffered.
// Blocks aren't synced; block A's waves publish e+1 into the SAME mirror
// slots while block B's comm still catches e -> B misses the mirror and
// waits on the agent copy (~700cy MALL). THAT is the residual wall.
// v15: mirror gets the v6 parity treatment (wsb[640+(e&1)*320]). Producer
// overwrites parity-p (epoch e) only at e+2, which requires its comm caught
// e+1 => all waves published e+1 => all waves applied e => EVERY block's
// comm finished catching e. Mirror words now provably live until consumed
// by all 8 comms -> the L2 fast path is reliable. With that, v12's adaptive
// cadence is re-enabled soundly: agent fallback every iteration until the
// mirror first validates (covers any exotic XCD mapping, Guideline 16),
// then every 4th iteration -> poll period ~370cy at L2 latency.
// Everything else identical to v11: dual publish, coalesced rank-major
// layout, hi-bits fast-path pops with u64-DPP tie fallback, LDS ring +
// monotone release tags, zero steady-state barriers, s_sleep(1) on miss.
// Exactness: u64 word order (dist desc, then lower global index) == ref
// argmax preference; unpublished words <= own-wave rank-5 <= vcutg; pop
// while W > vcutg; >=1 pop/epoch -> e <= 2047 (12-bit tag; 0xAA poison
// field 0xAAA=2730 never matches; stale words bit-identical by determinism).
// Numerics bit-exact: contract off, (dx*dx+dy*dy)+dz*dz, min via ?:, no fma.
__global__ __launch_bounds__(FPS_T)
__attribute__((amdgpu_waves_per_eu(1)))
void fps_kernel(const float* __restrict__ pts, float* __restrict__ out,
                ull* __restrict__ ws) {
#pragma clang fp contract(off)
    __shared__ float srx[RING], sry[RING], srz[RING];
    __shared__ unsigned rtag[RING];
    __shared__ unsigned etot;           // (epoch<<16) | last_posted_row

    const int blk = blockIdx.x;
    const int b = blk & 15;             // batch (round-robin: all 8 on 1 XCD)
    const int j = blk >> 4;             // block-within-batch 0..7
    const int tid = threadIdx.x;
    const int lane = tid & 63;
    const float* __restrict__ X = pts + (size_t)b * 3 * FPS_N;
    const float* __restrict__ Y = X + FPS_N;
    const float* __restrict__ Z = Y + FPS_N;
    const int off = j * PTS;
    float* __restrict__ outb = out + (size_t)b * 3 * FPS_M;
    ull* __restrict__ wsb = ws + (size_t)b * WSTRIDE;

    for (int q = tid; q < RING; q += FPS_T) rtag[q] = 0;
    if (tid == 0) etot = 0;
    __syncthreads();                    // only barrier (pre-loop)

    const float p0x = X[0], p0y = Y[0], p0z = Z[0];

    if (tid < 64) {
        // ================= comm wave =================
        if (j == 0 && lane == 0) {      // row 0 = point 0
            outb[0] = p0x; outb[FPS_M] = p0y; outb[2 * FPS_M] = p0z;
        }
        bool mir_seen = false;          // has the L2 mirror ever validated?
        int last = 0;
        for (unsigned e = 1; last < FPS_M - 1; ++e) {
            ull* const grp = wsb + (e & 1) * 320;          // agent (parity)
            ull* const mgr = wsb + 640 + (e & 1) * 320;    // mirror (parity)
            const ull ma0 = (ull)(uintptr_t)(mgr + 0 * 64 + lane);
            const ull ma1 = (ull)(uintptr_t)(mgr + 1 * 64 + lane);
            const ull ma2 = (ull)(uintptr_t)(mgr + 2 * 64 + lane);
            const ull ma3 = (ull)(uintptr_t)(mgr + 3 * 64 + lane);
            const ull mac = (ull)(uintptr_t)(mgr + 256 + lane);
            ull cv[KPUB];
            float ccx[KPUB], ccy[KPUB], ccz[KPUB];
#pragma unroll
            for (int c = 0; c < KPUB; ++c) {
                cv[c] = 0; ccx[c] = 0.0f; ccy[c] = 0.0f; ccz[c] = 0.0f;
            }
            unsigned kcm = 0;
            bool kw = false;
            ull cw = 0;
            for (int it = 0; it < (1 << 25); ++it) {
                // ---- stage 1: L2 fast path (coalesced sc0 reads) ----
                ull q0, q1, q2, q3, q4;
                asm volatile(
                    "global_load_dwordx2 %0, %5, off sc0\n\t"
                    "global_load_dwordx2 %1, %6, off sc0\n\t"
                    "global_load_dwordx2 %2, %7, off sc0\n\t"
                    "global_load_dwordx2 %3, %8, off sc0\n\t"
                    "global_load_dwordx2 %4, %9, off sc0\n\t"
                    "s_waitcnt vmcnt(0)"
                    : "=&v"(q0), "=&v"(q1), "=&v"(q2), "=&v"(q3), "=&v"(q4)
                    : "v"(ma0), "v"(ma1), "v"(ma2), "v"(ma3), "v"(mac)
                    : "memory");
                ull pv[KPUB + 1] = {q0, q1, q2, q3, q4};
#pragma unroll
                for (int c = 0; c < KPUB; ++c) {
                    if (!(kcm & (1u << c)) &&
                        (unsigned)(pv[c] & 0xFFFull) == e) {
                        cv[c] = pv[c];
                        kcm |= 1u << c;
                        mir_seen = true;
                        const int g = 32767 - (int)((pv[c] >> 17) & 0x7FFFull);
                        ccx[c] = X[g];  // prefetch during residual poll
                        ccy[c] = Y[g];
                        ccz[c] = Z[g];
                    }
                }
                if (!kw && (unsigned)(pv[KPUB] & 0xFFFull) == e) {
                    cw = pv[KPUB]; kw = true; mir_seen = true;
                }
                bool done = __all((kcm == ((1u << KPUB) - 1)) && kw);
                // adaptive cadence: mirror proven -> agent only every 4th it
                const bool slow = !done &&
                                  (!__any(mir_seen) || ((it & 3) == 3));
                if (slow) {
                    // ---- stage 2: agent fallback (correct on any XCD map) --
                    ull av[KPUB + 1];
#pragma unroll
                    for (int c = 0; c < KPUB; ++c)
                        av[c] = (kcm & (1u << c))
                                    ? 0
                                    : __hip_atomic_load(grp + c * 64 + lane,
                                                        __ATOMIC_RELAXED,
                                                        __HIP_MEMORY_SCOPE_AGENT);
                    av[KPUB] = kw ? 0
                                  : __hip_atomic_load(grp + 256 + lane,
                                                      __ATOMIC_RELAXED,
                                                      __HIP_MEMORY_SCOPE_AGENT);
#pragma unroll
                    for (int c = 0; c < KPUB; ++c) {
                        if (!(kcm & (1u << c)) &&
                            (unsigned)(av[c] & 0xFFFull) == e) {
                            cv[c] = av[c];
                            kcm |= 1u << c;
                            const int g =
                                32767 - (int)((av[c] >> 17) & 0x7FFFull);
                            ccx[c] = X[g];
                            ccy[c] = Y[g];
                            ccz[c] = Z[g];
                        }
                    }
                    if (!kw && (unsigned)(av[KPUB] & 0xFFFull) == e) {
                        cw = av[KPUB]; kw = true;
                    }
                    done = __all((kcm == ((1u << KPUB) - 1)) && kw);
                }
                if (done) break;
                __builtin_amdgcn_s_sleep(1);    // miss: free the SIMD
            }
            const ull vcutg = wave_max_u64(cw); // max of 64 wave rank-5s
            int posted = 0;
            while (last < FPS_M - 1 && posted < RING) {
                ull m = cv[0];
#pragma unroll
                for (int c = 1; c < KPUB; ++c)
                    if (cv[c] > m) m = cv[c];
                // hi-bits fast path for the wave max word; exact-tie fallback
                const unsigned mhi = (unsigned)(m >> 32);
                const unsigned Whi = wave_max_bits(mhi);
                const ull tb = __ballot(mhi == Whi);
                ull W;
                if (__popcll(tb) == 1) {
                    const int wl0 = (int)(__ffsll((long long)tb) - 1);
                    const unsigned wlo = (unsigned)__builtin_amdgcn_readlane(
                        (int)(unsigned)(m & 0xFFFFFFFFull), wl0);
                    W = ((ull)Whi << 32) | wlo;
                } else {
                    W = wave_max_u64(m);        // exact dist tie (rare)
                }
                if (W <= vcutg) break;
                bool own = false;
                float sx = 0.0f, sy = 0.0f, sz = 0.0f;
#pragma unroll
                for (int c = 0; c < KPUB; ++c) {
                    const bool h = (cv[c] == W);  // words globally unique
                    own |= h;
                    sx = h ? ccx[c] : sx;
                    sy = h ? ccy[c] : sy;
                    sz = h ? ccz[c] : sz;
                    cv[c] = h ? 0 : cv[c];        // consume
                }
                const ull mk = __ballot(own);     // exactly one bit
                const int wl = __ffsll((long long)mk) - 1;
                const float wx = readlane_f(sx, wl);
                const float wy = readlane_f(sy, wl);
                const float wz = readlane_f(sz, wl);
                // update pool (same IEEE ops as the batched apply)
#pragma unroll
                for (int c = 0; c < KPUB; ++c) {
                    float dx = ccx[c] - wx, dy = ccy[c] - wy, dz = ccz[c] - wz;
                    float d = (dx * dx + dy * dy) + dz * dz;
                    float df = __uint_as_float((unsigned)(cv[c] >> 32));
                    float nd = d < df ? d : df;   // consumed (0) stays 0
                    cv[c] = ((ull)__float_as_uint(nd) << 32)
                          | (cv[c] & 0xFFFFFFFFull);
                }
                ++last; ++posted;
                const int slot = last & (RING - 1);
                if (lane == 0) {                  // post to ring, release tag
                    srx[slot] = wx; sry[slot] = wy; srz[slot] = wz;
                    __hip_atomic_store(&rtag[slot], (unsigned)last,
                                       __ATOMIC_RELEASE,
                                       __HIP_MEMORY_SCOPE_WORKGROUP);
                }
            }
            if (lane == 0)
                __hip_atomic_store(&etot, (e << 16) | (unsigned)last,
                                   __ATOMIC_RELAXED, __HIP_MEMORY_SCOPE_WORKGROUP);
        }
    } else {
        // ================= scan waves =================
        const int st = tid - 64;        // 0..511
        const int w = (tid >> 6) - 1;   // scan wave 0..7
        const int wid = j * 8 + w;      // wave id within batch 0..63
        float cx[PPT], cy[PPT], cz[PPT], dist[PPT];
#pragma unroll
        for (int k = 0; k < PPT; ++k) { // coords in regs; apply p0 inline
            const int g = off + k * SCT + st;
            cx[k] = X[g]; cy[k] = Y[g]; cz[k] = Z[g];
            float dx = cx[k] - p0x, dy = cy[k] - p0y, dz = cz[k] - p0z;
            dist[k] = (dx * dx + dy * dy) + dz * dz;
        }
        const int goff = off + st;      // g(k) = goff + k*SCT, increasing in k
        unsigned applied = 0;
        for (unsigned e = 1;; ++e) {
            ull* const grp = wsb + (e & 1) * 320;          // agent (parity)
            ull* const mgr = wsb + 640 + (e & 1) * 320;    // mirror (parity)
            // ---- B: top-5 extraction (bit-compares; exact tie resolve) ----
            float fd[PPT];
#pragma unroll
            for (int k = 0; k < PPT; ++k) fd[k] = dist[k];
            for (int r = 0; r < KPUB + 1; ++r) {
                float m = fd[0];
#pragma unroll
                for (int k = 1; k < PPT; ++k) m = fmaxf(m, fd[k]);
                const unsigned Wb = wave_max_bits(__float_as_uint(m));
                // lane-local lowest-index holder of W (descending overwrite)
                unsigned mg = 0xFFFFFFFFu;
#pragma unroll
                for (int k = PPT - 1; k >= 0; --k)
                    if (__float_as_uint(fd[k]) == Wb)
                        mg = (unsigned)(goff + k * SCT);
                const ull mk = __ballot(mg != 0xFFFFFFFFu);   // >= 1 bit
                unsigned gw;
                if (__popcll(mk) == 1) {          // unique holder (common)
                    gw = (unsigned)__builtin_amdgcn_readlane(
                        (int)mg, (int)(__ffsll((long long)mk) - 1));
                } else {                          // exact dist tie (rare)
                    gw = wave_min_u32(mg);
                }
                const ull word = ((ull)Wb << 32)
                               | ((ull)(32767u - gw) << 17) | (ull)e;
                if (r < KPUB) {
#pragma unroll
                    for (int k = 0; k < PPT; ++k)  // mask exactly the winner
                        if ((unsigned)(goff + k * SCT) == gw)
                            fd[k] = -1.0f;         // < every real dist (>=+0)
                    if (lane == r) {               // dual publish: L2 + agent
                        __hip_atomic_store(mgr + r * 64 + wid, word,
                                           __ATOMIC_RELAXED,
                                           __HIP_MEMORY_SCOPE_WORKGROUP);
                        __hip_atomic_store(grp + r * 64 + wid, word,
                                           __ATOMIC_RELAXED,
                                           __HIP_MEMORY_SCOPE_AGENT);
                    }
                } else {
                    if (lane == KPUB) {            // the cut (rank-5)
                        __hip_atomic_store(mgr + 256 + wid, word,
                                           __ATOMIC_RELAXED,
                                           __HIP_MEMORY_SCOPE_WORKGROUP);
                        __hip_atomic_store(grp + 256 + wid, word,
                                           __ATOMIC_RELAXED,
                                           __HIP_MEMORY_SCOPE_AGENT);
                    }
                }
            }
            // ---- apply: consume ring entries as posted; sleep when idle ----
            unsigned last_row = 0;
            bool have = false;
            for (;;) {
                bool did = false;
                if (!have) {
                    unsigned u = __hip_atomic_load(&etot, __ATOMIC_RELAXED,
                                                   __HIP_MEMORY_SCOPE_WORKGROUP);
                    if ((u >> 16) == e) { last_row = u & 0xFFFFu; have = true; did = true; }
                }
                const unsigned want = applied + 1;
                if (!have || want <= last_row) {
                    const int slot = (int)(want & (RING - 1));
                    if (__hip_atomic_load(&rtag[slot], __ATOMIC_ACQUIRE,
                                          __HIP_MEMORY_SCOPE_WORKGROUP) == want) {
                        const float wx = srx[slot], wy = sry[slot], wz = srz[slot];
#pragma unroll
                        for (int k = 0; k < PPT; ++k) {
                            float dx = cx[k] - wx, dy = cy[k] - wy, dz = cz[k] - wz;
                            float d = (dx * dx + dy * dy) + dz * dz;
                            dist[k] = d < dist[k] ? d : dist[k];
                        }
                        if (j == 0 && w == 0 && lane < 3) {   // emit row
                            float cvv = lane == 0 ? wx : (lane == 1 ? wy : wz);
                            outb[(size_t)lane * FPS_M + want] = cvv;
                        }
                        applied = want;
                        did = true;
                    }
                }
                if (have && applied == last_row) break;
                if (!did) __builtin_amdgcn_s_sleep(1);  // idle: free the SIMD
            }
            if (last_row >= FPS_M - 1) break;
        }
    }
}

extern "C" void kernel_launch(void* const* d_in, const int* in_sizes, int n_in,
                              void* d_out, int out_size, void* d_ws, size_t ws_size,
                              hipStream_t stream) {
    const float* pts = (const float*)d_in[0];   // [16, 3, 32768] fp32
    float* out = (float*)d_out;                 // [16, 3, 2048] fp32
    ull* ws = (ull*)d_ws;                       // 16 x 1280 words = 160 KB used
    void* args[] = { (void*)&pts, (void*)&out, (void*)&ws };
    hipLaunchCooperativeKernel((const void*)fps_kernel,
                               dim3(FPS_B * BLK_PER_B), dim3(FPS_T),
                               args, 0, stream);
}

// Round 10
// 1115.320 us; speedup vs baseline: 1.0431x; 1.0431x over previous
//
#include <hip/hip_runtime.h>

#define FPS_N 32768
#define FPS_M 2048
#define FPS_B 16
#define BLK_PER_B 8
#define FPS_T 576                 // 9 waves: wave 0 = comm, waves 1-8 = scan
#define SCT 512                   // scan threads
#define PTS (FPS_N / BLK_PER_B)   // 4096 points per block
#define PPT (PTS / SCT)           // 8 points per scan thread
#define KPUB 4                    // candidates published per wave
#define RING 128
#define WSTRIDE 960               // 2 parities x 320 (agent) + 320 (L2 mirror)

typedef unsigned long long ull;

// u64 max step via DPP (identity-safe: old = self). Verified rounds 11/15-17.
#define DPP_MAX_STEP(ctrl, rmask)                                              \
    {                                                                          \
        unsigned plo = (unsigned)__builtin_amdgcn_update_dpp(                  \
            (int)lo, (int)lo, (ctrl), (rmask), 0xf, false);                    \
        unsigned phi = (unsigned)__builtin_amdgcn_update_dpp(                  \
            (int)hi, (int)hi, (ctrl), (rmask), 0xf, false);                    \
        if (phi > hi || (phi == hi && plo > lo)) { hi = phi; lo = plo; }       \
    }

__device__ __forceinline__ ull wave_max_u64(ull v) {
    unsigned lo = (unsigned)v, hi = (unsigned)(v >> 32);
    DPP_MAX_STEP(0x111, 0xf)
    DPP_MAX_STEP(0x112, 0xf)
    DPP_MAX_STEP(0x114, 0xf)
    DPP_MAX_STEP(0x118, 0xf)
    DPP_MAX_STEP(0x142, 0xa)
    DPP_MAX_STEP(0x143, 0xc)
    unsigned blo = (unsigned)__builtin_amdgcn_readlane((int)lo, 63);
    unsigned bhi = (unsigned)__builtin_amdgcn_readlane((int)hi, 63);
    return ((ull)bhi << 32) | blo;
}

// Wave max of f32 BITS over the domain {non-negative f32, -1.0f sentinel}:
// signed-int order == float order there. 4 row_shr DPP steps accumulate the
// row max toward HIGHER lanes, so after 1/2/4/8 the row max sits in lane
// 15/31/47/63. Verified on HW (v8/v9/v11 runs, absmax 0.0).
__device__ __forceinline__ unsigned wave_max_bits(unsigned v) {
    int m = (int)v;
#define DPP_IMAX_STEP(ctrl)                                                    \
    {                                                                          \
        int p = __builtin_amdgcn_update_dpp((int)m, (int)m, (ctrl), 0xf, 0xf,  \
                                            false);                            \
        m = p > m ? p : m;                                                     \
    }
    DPP_IMAX_STEP(0x111)   // row_shr:1
    DPP_IMAX_STEP(0x112)   // row_shr:2
    DPP_IMAX_STEP(0x114)   // row_shr:4
    DPP_IMAX_STEP(0x118)   // row_shr:8 -> lane 15 of each row = row max
    int r0 = __builtin_amdgcn_readlane(m, 15);
    int r1 = __builtin_amdgcn_readlane(m, 31);
    int r2 = __builtin_amdgcn_readlane(m, 47);
    int r3 = __builtin_amdgcn_readlane(m, 63);
    int a = r0 > r1 ? r0 : r1;
    int bq = r2 > r3 ? r2 : r3;
    return (unsigned)(a > bq ? a : bq);
}

// u32 wave min (identity-safe), broadcast from lane 63. Rare-tie path only.
__device__ __forceinline__ unsigned wave_min_u32(unsigned v) {
    unsigned m = v;
#define DPP_UMIN_STEP(ctrl, rmask)                                             \
    {                                                                          \
        unsigned p = (unsigned)__builtin_amdgcn_update_dpp(                    \
            (int)m, (int)m, (ctrl), (rmask), 0xf, false);                      \
        if (p < m) m = p;                                                      \
    }
    DPP_UMIN_STEP(0x111, 0xf)
    DPP_UMIN_STEP(0x112, 0xf)
    DPP_UMIN_STEP(0x114, 0xf)
    DPP_UMIN_STEP(0x118, 0xf)
    DPP_UMIN_STEP(0x142, 0xa)
    DPP_UMIN_STEP(0x143, 0xc)
    return (unsigned)__builtin_amdgcn_readlane((int)m, 63);
}

__device__ __forceinline__ float readlane_f(float v, int l) {
    return __uint_as_float(
        (unsigned)__builtin_amdgcn_readlane((int)__float_as_uint(v), l));
}

// EXACT LAZY-BATCHED FPS v16 == v11 (empirical optimum, re-anchored).
// Session ledger: v9 coalesced rank-major mailbox 1493->1157; v11 dual-path
// (L2 mirror + agent, both polled EVERY iteration) 1157->1124 (1065 steady)
// — BEST. All subsequent single-variable probes lost: v12 agent-throttle
// -90us (agent delivers the critical words); v13 contiguous batch map -45us
// + FETCH x12 (dispatch is round-robin blk%8 -> v11's b=blk&15 already
// groups each batch on one XCD); v14 split-counter overlapped poll flat
// (poll period not binding); v15 parity-buffered mirror + cadence -50us
// (falsifies laggard-overwrite theory; the agent-cadence term itself is
// what matters). Conclusion: comm-axis measured-exhausted; v11 is the
// optimum. Structural floor ~890 serial epochs x ~2870cy = ~1065us steady.
// Protocol (v11): scan waves publish top-4+cut per epoch, DUAL-published:
// plain store to single-buffered L2 mirror (wsb[640..960)) + agent-scope
// store to parity-buffered copy (wsb[(e&1)*320..+320), v6 overwrite-safety:
// slot reused only at e+2 after every comm caught e). Comm polls mirror via
// asm global_load_dwordx2 sc0 (coalesced 512B reads) then agent fallback
// the same iteration (correct under ANY block->XCD mapping, Guideline 16).
// Words self-validate (12-bit epoch tag; 0xAA poison field 0xAAA=2730 never
// matches; stale words bit-identical by determinism). Comm pops while
// W > vcutg (max of 64 rank-5 cuts), posts to LDS ring (monotone release
// tags); scans apply as posted; zero steady-state barriers; s_sleep(1) on
// every spin miss. Exactness: u64 word order (dist desc, lower global index
// wins ties) == reference argmax preference; unpublished words <= own-wave
// rank-5 <= vcutg; >=1 pop/epoch -> e <= 2047.
// Numerics bit-exact: contract off, (dx*dx+dy*dy)+dz*dz, min via ?:, no fma.
__global__ __launch_bounds__(FPS_T)
__attribute__((amdgpu_waves_per_eu(1)))
void fps_kernel(const float* __restrict__ pts, float* __restrict__ out,
                ull* __restrict__ ws) {
#pragma clang fp contract(off)
    __shared__ float srx[RING], sry[RING], srz[RING];
    __shared__ unsigned rtag[RING];
    __shared__ unsigned etot;           // (epoch<<16) | last_posted_row

    const int blk = blockIdx.x;
    const int b = blk & 15;             // batch (round-robin: all 8 on 1 XCD)
    const int j = blk >> 4;             // block-within-batch 0..7
    const int tid = threadIdx.x;
    const int lane = tid & 63;
    const float* __restrict__ X = pts + (size_t)b * 3 * FPS_N;
    const float* __restrict__ Y = X + FPS_N;
    const float* __restrict__ Z = Y + FPS_N;
    const int off = j * PTS;
    float* __restrict__ outb = out + (size_t)b * 3 * FPS_M;
    ull* __restrict__ wsb = ws + (size_t)b * WSTRIDE;
    ull* __restrict__ mir = wsb + 640;  // L2 mirror (single-buffered)

    for (int q = tid; q < RING; q += FPS_T) rtag[q] = 0;
    if (tid == 0) etot = 0;
    __syncthreads();                    // only barrier (pre-loop)

    const float p0x = X[0], p0y = Y[0], p0z = Z[0];

    if (tid < 64) {
        // ================= comm wave =================
        if (j == 0 && lane == 0) {      // row 0 = point 0
            outb[0] = p0x; outb[FPS_M] = p0y; outb[2 * FPS_M] = p0z;
        }
        // mirror lane addresses — loop-invariant
        const ull ma0 = (ull)(uintptr_t)(mir + 0 * 64 + lane);
        const ull ma1 = (ull)(uintptr_t)(mir + 1 * 64 + lane);
        const ull ma2 = (ull)(uintptr_t)(mir + 2 * 64 + lane);
        const ull ma3 = (ull)(uintptr_t)(mir + 3 * 64 + lane);
        const ull mac = (ull)(uintptr_t)(mir + 256 + lane);
        int last = 0;
        for (unsigned e = 1; last < FPS_M - 1; ++e) {
            ull* const grp = wsb + (e & 1) * 320;   // agent copy (parity)
            ull cv[KPUB];
            float ccx[KPUB], ccy[KPUB], ccz[KPUB];
#pragma unroll
            for (int c = 0; c < KPUB; ++c) {
                cv[c] = 0; ccx[c] = 0.0f; ccy[c] = 0.0f; ccz[c] = 0.0f;
            }
            unsigned kcm = 0;
            bool kw = false;
            ull cw = 0;
            for (int it = 0; it < (1 << 25); ++it) {
                // ---- stage 1: L2 fast path (coalesced sc0 reads) ----
                ull q0, q1, q2, q3, q4;
                asm volatile(
                    "global_load_dwordx2 %0, %5, off sc0\n\t"
                    "global_load_dwordx2 %1, %6, off sc0\n\t"
                    "global_load_dwordx2 %2, %7, off sc0\n\t"
                    "global_load_dwordx2 %3, %8, off sc0\n\t"
                    "global_load_dwordx2 %4, %9, off sc0\n\t"
                    "s_waitcnt vmcnt(0)"
                    : "=&v"(q0), "=&v"(q1), "=&v"(q2), "=&v"(q3), "=&v"(q4)
                    : "v"(ma0), "v"(ma1), "v"(ma2), "v"(ma3), "v"(mac)
                    : "memory");
                ull pv[KPUB + 1] = {q0, q1, q2, q3, q4};
#pragma unroll
                for (int c = 0; c < KPUB; ++c) {
                    if (!(kcm & (1u << c)) &&
                        (unsigned)(pv[c] & 0xFFFull) == e) {
                        cv[c] = pv[c];
                        kcm |= 1u << c;
                        const int g = 32767 - (int)((pv[c] >> 17) & 0x7FFFull);
                        ccx[c] = X[g];  // prefetch during residual poll
                        ccy[c] = Y[g];
                        ccz[c] = Z[g];
                    }
                }
                if (!kw && (unsigned)(pv[KPUB] & 0xFFFull) == e) {
                    cw = pv[KPUB]; kw = true;
                }
                bool done = __all((kcm == ((1u << KPUB) - 1)) && kw);
                if (!done) {
                    // ---- stage 2: agent fallback (correct on any XCD map) --
                    ull av[KPUB + 1];
#pragma unroll
                    for (int c = 0; c < KPUB; ++c)
                        av[c] = (kcm & (1u << c))
                                    ? 0
                                    : __hip_atomic_load(grp + c * 64 + lane,
                                                        __ATOMIC_RELAXED,
                                                        __HIP_MEMORY_SCOPE_AGENT);
                    av[KPUB] = kw ? 0
                                  : __hip_atomic_load(grp + 256 + lane,
                                                      __ATOMIC_RELAXED,
                                                      __HIP_MEMORY_SCOPE_AGENT);
#pragma unroll
                    for (int c = 0; c < KPUB; ++c) {
                        if (!(kcm & (1u << c)) &&
                            (unsigned)(av[c] & 0xFFFull) == e) {
                            cv[c] = av[c];
                            kcm |= 1u << c;
                            const int g =
                                32767 - (int)((av[c] >> 17) & 0x7FFFull);
                            ccx[c] = X[g];
                            ccy[c] = Y[g];
                            ccz[c] = Z[g];
                        }
                    }
                    if (!kw && (unsigned)(av[KPUB] & 0xFFFull) == e) {
                        cw = av[KPUB]; kw = true;
                    }
                    done = __all((kcm == ((1u << KPUB) - 1)) && kw);
                }
                if (done) break;
                __builtin_amdgcn_s_sleep(1);    // miss: free the SIMD
            }
            const ull vcutg = wave_max_u64(cw); // max of 64 wave rank-5s
            int posted = 0;
            while (last < FPS_M - 1 && posted < RING) {
                ull m = cv[0];
#pragma unroll
                for (int c = 1; c < KPUB; ++c)
                    if (cv[c] > m) m = cv[c];
                // hi-bits fast path for the wave max word; exact-tie fallback
                const unsigned mhi = (unsigned)(m >> 32);
                const unsigned Whi = wave_max_bits(mhi);
                const ull tb = __ballot(mhi == Whi);
                ull W;
                if (__popcll(tb) == 1) {
                    const int wl0 = (int)(__ffsll((long long)tb) - 1);
                    const unsigned wlo = (unsigned)__builtin_amdgcn_readlane(
                        (int)(unsigned)(m & 0xFFFFFFFFull), wl0);
                    W = ((ull)Whi << 32) | wlo;
                } else {
                    W = wave_max_u64(m);        // exact dist tie (rare)
                }
                if (W <= vcutg) break;
                bool own = false;
                float sx = 0.0f, sy = 0.0f, sz = 0.0f;
#pragma unroll
                for (int c = 0; c < KPUB; ++c) {
                    const bool h = (cv[c] == W);  // words globally unique
                    own |= h;
                    sx = h ? ccx[c] : sx;
                    sy = h ? ccy[c] : sy;
                    sz = h ? ccz[c] : sz;
                    cv[c] = h ? 0 : cv[c];        // consume
                }
                const ull mk = __ballot(own);     // exactly one bit
                const int wl = __ffsll((long long)mk) - 1;
                const float wx = readlane_f(sx, wl);
                const float wy = readlane_f(sy, wl);
                const float wz = readlane_f(sz, wl);
                // update pool (same IEEE ops as the batched apply)
#pragma unroll
                for (int c = 0; c < KPUB; ++c) {
                    float dx = ccx[c] - wx, dy = ccy[c] - wy, dz = ccz[c] - wz;
                    float d = (dx * dx + dy * dy) + dz * dz;
                    float df = __uint_as_float((unsigned)(cv[c] >> 32));
                    float nd = d < df ? d : df;   // consumed (0) stays 0
                    cv[c] = ((ull)__float_as_uint(nd) << 32)
                          | (cv[c] & 0xFFFFFFFFull);
                }
                ++last; ++posted;
                const int slot = last & (RING - 1);
                if (lane == 0) {                  // post to ring, release tag
                    srx[slot] = wx; sry[slot] = wy; srz[slot] = wz;
                    __hip_atomic_store(&rtag[slot], (unsigned)last,
                                       __ATOMIC_RELEASE,
                                       __HIP_MEMORY_SCOPE_WORKGROUP);
                }
            }
            if (lane == 0)
                __hip_atomic_store(&etot, (e << 16) | (unsigned)last,
                                   __ATOMIC_RELAXED, __HIP_MEMORY_SCOPE_WORKGROUP);
        }
    } else {
        // ================= scan waves =================
        const int st = tid - 64;        // 0..511
        const int w = (tid >> 6) - 1;   // scan wave 0..7
        const int wid = j * 8 + w;      // wave id within batch 0..63
        float cx[PPT], cy[PPT], cz[PPT], dist[PPT];
#pragma unroll
        for (int k = 0; k < PPT; ++k) { // coords in regs; apply p0 inline
            const int g = off + k * SCT + st;
            cx[k] = X[g]; cy[k] = Y[g]; cz[k] = Z[g];
            float dx = cx[k] - p0x, dy = cy[k] - p0y, dz = cz[k] - p0z;
            dist[k] = (dx * dx + dy * dy) + dz * dz;
        }
        const int goff = off + st;      // g(k) = goff + k*SCT, increasing in k
        unsigned applied = 0;
        for (unsigned e = 1;; ++e) {
            ull* const grp = wsb + (e & 1) * 320;   // agent copy (parity)
            // ---- B: top-5 extraction (bit-compares; exact tie resolve) ----
            float fd[PPT];
#pragma unroll
            for (int k = 0; k < PPT; ++k) fd[k] = dist[k];
            for (int r = 0; r < KPUB + 1; ++r) {
                float m = fd[0];
#pragma unroll
                for (int k = 1; k < PPT; ++k) m = fmaxf(m, fd[k]);
                const unsigned Wb = wave_max_bits(__float_as_uint(m));
                // lane-local lowest-index holder of W (descending overwrite)
                unsigned mg = 0xFFFFFFFFu;
#pragma unroll
                for (int k = PPT - 1; k >= 0; --k)
                    if (__float_as_uint(fd[k]) == Wb)
                        mg = (unsigned)(goff + k * SCT);
                const ull mk = __ballot(mg != 0xFFFFFFFFu);   // >= 1 bit
                unsigned gw;
                if (__popcll(mk) == 1) {          // unique holder (common)
                    gw = (unsigned)__builtin_amdgcn_readlane(
                        (int)mg, (int)(__ffsll((long long)mk) - 1));
                } else {                          // exact dist tie (rare)
                    gw = wave_min_u32(mg);
                }
                const ull word = ((ull)Wb << 32)
                               | ((ull)(32767u - gw) << 17) | (ull)e;
                if (r < KPUB) {
#pragma unroll
                    for (int k = 0; k < PPT; ++k)  // mask exactly the winner
                        if ((unsigned)(goff + k * SCT) == gw)
                            fd[k] = -1.0f;         // < every real dist (>=+0)
                    if (lane == r) {               // dual publish: L2 + agent
                        __hip_atomic_store(mir + r * 64 + wid, word,
                                           __ATOMIC_RELAXED,
                                           __HIP_MEMORY_SCOPE_WORKGROUP);
                        __hip_atomic_store(grp + r * 64 + wid, word,
                                           __ATOMIC_RELAXED,
                                           __HIP_MEMORY_SCOPE_AGENT);
                    }
                } else {
                    if (lane == KPUB) {            // the cut (rank-5)
                        __hip_atomic_store(mir + 256 + wid, word,
                                           __ATOMIC_RELAXED,
                                           __HIP_MEMORY_SCOPE_WORKGROUP);
                        __hip_atomic_store(grp + 256 + wid, word,
                                           __ATOMIC_RELAXED,
                                           __HIP_MEMORY_SCOPE_AGENT);
                    }
                }
            }
            // ---- apply: consume ring entries as posted; sleep when idle ----
            unsigned last_row = 0;
            bool have = false;
            for (;;) {
                bool did = false;
                if (!have) {
                    unsigned u = __hip_atomic_load(&etot, __ATOMIC_RELAXED,
                                                   __HIP_MEMORY_SCOPE_WORKGROUP);
                    if ((u >> 16) == e) { last_row = u & 0xFFFFu; have = true; did = true; }
                }
                const unsigned want = applied + 1;
                if (!have || want <= last_row) {
                    const int slot = (int)(want & (RING - 1));
                    if (__hip_atomic_load(&rtag[slot], __ATOMIC_ACQUIRE,
                                          __HIP_MEMORY_SCOPE_WORKGROUP) == want) {
                        const float wx = srx[slot], wy = sry[slot], wz = srz[slot];
#pragma unroll
                        for (int k = 0; k < PPT; ++k) {
                            float dx = cx[k] - wx, dy = cy[k] - wy, dz = cz[k] - wz;
                            float d = (dx * dx + dy * dy) + dz * dz;
                            dist[k] = d < dist[k] ? d : dist[k];
                        }
                        if (j == 0 && w == 0 && lane < 3) {   // emit row
                            float cvv = lane == 0 ? wx : (lane == 1 ? wy : wz);
                            outb[(size_t)lane * FPS_M + want] = cvv;
                        }
                        applied = want;
                        did = true;
                    }
                }
                if (have && applied == last_row) break;
                if (!did) __builtin_amdgcn_s_sleep(1);  // idle: free the SIMD
            }
            if (last_row >= FPS_M - 1) break;
        }
    }
}

extern "C" void kernel_launch(void* const* d_in, const int* in_sizes, int n_in,
                              void* d_out, int out_size, void* d_ws, size_t ws_size,
                              hipStream_t stream) {
    const float* pts = (const float*)d_in[0];   // [16, 3, 32768] fp32
    float* out = (float*)d_out;                 // [16, 3, 2048] fp32
    ull* ws = (ull*)d_ws;                       // 16 x 960 words = 120 KB used
    void* args[] = { (void*)&pts, (void*)&out, (void*)&ws };
    hipLaunchCooperativeKernel((const void*)fps_kernel,
                               dim3(FPS_B * BLK_PER_B), dim3(FPS_T),
                               args, 0, stream);
}